// Round 7
// baseline (303.214 us; speedup 1.0000x reference)
//
#include <hip/hip_runtime.h>

typedef __attribute__((ext_vector_type(8))) short short8;
typedef __attribute__((ext_vector_type(4))) float f32x4;
typedef __attribute__((ext_vector_type(16))) float f32x16;
typedef unsigned short u16;
typedef unsigned int u32;

#define NB_TOT 8192
#define DIM 192

// ws byte offsets (prep outputs only)
#define WN_OFF    0          // [576][192] bf16 qkv_w (n-major)
#define WCN_OFF   221184     // [192][192] bf16 nn1_w@attn_w (n-major)
#define BC_OFF    294912     // [192] f32
#define KRELF_OFF 295680     // [17][4][64][8] bf16 rel B-frags
#define MPA_OFF   365312     // [289] f32 mask*PA

// fused LDS (u16 units), block = 1 batch (17 rows, 3 bh), 256 threads (4 waves)
// 26,576 B -> alloc 26,624; x6 = 159,744 LDS-wise; regs (~124 unified) give 4
// blocks/CU = 16 waves in 4 INDEPENDENT phase streams (vs v7's 2):
//   XSF @ 0     : x[17][200] bf16 (GEMM A-rows >=17 read in-bounds garbage, discarded)
//                 overlay1: Sf f32[867] @ 0 + Sf2 f32[867] @ u16 1734 (after x dead)
//                 overlay2: ao [17][200] (born at PV, read by out-proj)
//   K   @ 3472  : k slots [bh][17][64] XOR-swizzled (col ^ ((row&7)<<3)), stride 1088
//                 overlay: wbf u16[51*32] + dropl f32[51] (k dead after merged phase)
//   V   @ 6736  : v slots [bh][17][64] plain, stride 1088
//   Q   @ 10000 : q slots [bh][17][64] XOR-swizzled, stride 1096 (8-u16 inter-slot pad)
#define XS_O  0
#define SF2_U16 1734
#define K_O   3472
#define V_O   6736
#define Q_O   10000
#define SMEM_U16 13288

__device__ __forceinline__ u16 f2b(float f) {
  u32 u = __float_as_uint(f);
  u32 r = u + 0x7FFFu + ((u >> 16) & 1u);  // RNE
  return (u16)(r >> 16);
}

// LDS-only barrier (global ops have register data-deps; final stores need no drain)
__device__ __forceinline__ void bar_lgkm() {
  asm volatile("s_waitcnt lgkmcnt(0)" ::: "memory");
  __builtin_amdgcn_s_barrier();
  asm volatile("" ::: "memory");
}

__global__ void prep_kernel(const float* __restrict__ qkv_w,
                            const float* __restrict__ attn_w,
                            const float* __restrict__ attn_b,
                            const float* __restrict__ nn1_w,
                            const float* __restrict__ nn1_b,
                            const float* __restrict__ key_rel,
                            const float* __restrict__ krd,
                            const float* __restrict__ mask,
                            const float* __restrict__ PA,
                            char* __restrict__ ws) {
  u16* wN    = (u16*)(ws + WN_OFF);
  u16* wcN   = (u16*)(ws + WCN_OFF);
  float* bc  = (float*)(ws + BC_OFF);
  u16* krelf = (u16*)(ws + KRELF_OFF);
  float* mpa = (float*)(ws + MPA_OFF);
  for (int idx = blockIdx.x * 256 + threadIdx.x; idx < 152289; idx += gridDim.x * 256) {
    if (idx < 110592) {
      wN[idx] = f2b(qkv_w[idx]);
    } else if (idx < 147456) {
      int t2 = idx - 110592; int n = t2 / 192, k = t2 - n * 192;
      float a = 0.f;
      for (int t = 0; t < 192; ++t) a = fmaf(nn1_w[n * 192 + t], attn_w[t * 192 + k], a);
      wcN[n * 192 + k] = f2b(a);
    } else if (idx < 147648) {
      int n = idx - 147456; float a = nn1_b[n];
      for (int t = 0; t < 192; ++t) a = fmaf(nn1_w[n * 192 + t], attn_b[t], a);
      bc[n] = a;
    } else if (idx < 152000) {
      int t = idx - 147648;              // ((I*4+ks)*64 + lane)
      int lane = t & 63, ks = (t >> 6) & 3, I = t >> 8;
      int J = lane & 31;
      int d0 = ks * 16 + (lane >> 5) * 8;
      u16 vals[8];
#pragma unroll
      for (int i = 0; i < 8; ++i) {
        float v = 0.f;
        if (J <= 16) {
          if (J == I) v = krd[d0 + i];
          else { int tt = 17 * I + J; int p = tt - tt / 18 - 1; v = key_rel[p * 64 + d0 + i]; }
        }
        vals[i] = f2b(v);
      }
      u32 w0 = vals[0] | ((u32)vals[1] << 16), w1 = vals[2] | ((u32)vals[3] << 16);
      u32 w2 = vals[4] | ((u32)vals[5] << 16), w3 = vals[6] | ((u32)vals[7] << 16);
      uint4 pk; pk.x = w0; pk.y = w1; pk.z = w2; pk.w = w3;
      *(uint4*)(krelf + (size_t)t * 8) = pk;
    } else {
      int i = idx - 152000; mpa[i] = mask[i] * PA[i];
    }
  }
}

// ---------------- fused v9: 1 batch/block, 4 waves, 4+ independent blocks/CU ----------------
__global__ __launch_bounds__(256, 4)
void fused_kernel(const float* __restrict__ x, const float* __restrict__ gm,
                  const float* __restrict__ drop, const float* __restrict__ qkv_b,
                  const u16* __restrict__ wN, const u16* __restrict__ wcN,
                  const float* __restrict__ bc, const u16* __restrict__ krelf,
                  const float* __restrict__ mpa, float* __restrict__ out) {
  __shared__ u16 smem[SMEM_U16];
  float* const Sf    = (float*)(smem + XS_O);        // 867 f32 overlay (after GEMM)
  float* const Sf2   = (float*)(smem + SF2_U16);     // 867 f32 (rel + mpa), same overlay
  u16*   const wbf   = smem + K_O;                   // 51*32 u16 overlay (after merged)
  float* const dropl = (float*)(smem + K_O + 1632);  // 51 f32, after wbf in dead-K

  const int tid = threadIdx.x;
  const int blk = blockIdx.x;
  const int lane = tid & 63;
  const int l31 = lane & 31;
  const int lh = lane >> 5;
  const int wv = tid >> 6;   // 0..3

  // ---- prefetch: drop (1 reg) + gm softmax-slice (5 regs/thread) ----
  float drv = 0.f;
  if (tid < 51) drv = drop[(size_t)blk * 51 + tid];
  float gmr5[5] = {0.f, 0.f, 0.f, 0.f, 0.f};
  if (tid < 204) {
    int r = tid >> 2, sub = tid & 3;
    int bh = r / 17, I = r - bh * 17;
    const float* gmrow = gm + (size_t)blk * 867 + bh * 289 + I * 17;
#pragma unroll
    for (int i = 0; i < 5; ++i) {
      int J = sub + 4 * i;
      if (J < 17) gmr5[i] = gmrow[J];
    }
  }

  // ---- stage x -> LDS bf16 [17][200] ----
  const float* xb = x + (size_t)blk * 17 * 192;
  for (int idx = tid; idx < 816; idx += 256) {
    int row = idx / 48, k4 = (idx - row * 48) * 4;
    float4 v = *(const float4*)(xb + row * 192 + k4);
    u16 p[4] = {f2b(v.x), f2b(v.y), f2b(v.z), f2b(v.w)};
    *(uint2*)(smem + XS_O + row * 200 + k4) = *(uint2*)p;
  }
  bar_lgkm();

  const int lrow = tid & 15, lg = (tid >> 4) & 3, kgrp = lg * 8;

  // ---- qkv GEMM: 36 N-tiles of 16 cols across 4 waves; B-frags reg-resident,
  //      reused over 2 M-tiles (rows 0-15, 16-31; rows >=17 garbage, discarded) ----
  for (int N = wv; N < 36; N += 4) {
    const int c0 = N * 16;
    const int which = c0 / 192;
    const int hd = c0 - which * 192;
    const int h = hd >> 6;
    const int d = (hd & 63) + lrow;
    const int c = c0 + lrow;
    const u16* wB = wN + (size_t)c * 192;
    short8 bfr[6];
#pragma unroll
    for (int kk = 0; kk < 6; ++kk)
      bfr[kk] = *(const short8*)(wB + kk * 32 + kgrp);
    const float bias = qkv_b[c];
    const float scale = which ? 1.0f : 0.125f;
#pragma unroll
    for (int m = 0; m < 2; ++m) {
      f32x4 acc = {};
#pragma unroll
      for (int kk = 0; kk < 6; ++kk) {
        short8 a = *(const short8*)(smem + XS_O + (m * 16 + lrow) * 200 + kk * 32 + kgrp);
        acc = __builtin_amdgcn_mfma_f32_16x16x32_bf16(a, bfr[kk], acc, 0, 0, 0);
      }
#pragma unroll
      for (int j = 0; j < 4; ++j) {
        int I = m * 16 + lg * 4 + j;
        if (I < 17) {
          u16 val = f2b((acc[j] + bias) * scale);
          if (which == 0)      smem[Q_O + h * 1096 + I * 64 + (d ^ ((I & 7) << 3))] = val;
          else if (which == 1) smem[K_O + h * 1088 + I * 64 + (d ^ ((I & 7) << 3))] = val;
          else                 smem[V_O + h * 1088 + I * 64 + d] = val;
        }
      }
    }
  }
  bar_lgkm();   // q/k/v complete; x dead -> Sf/Sf2 may overlay

  const int rowc = l31 < 16 ? l31 : 16;

  // ==== MERGED phase: QK^T (waves 0-2, -> Sf, C-init 0) || rel+mpa (all waves,
  //      -> Sf2) || dropl park. Disjoint output buffers -> no ordering needed. ====
  if (wv < 3) {
    int bh = wv;
    const u16* qb = smem + Q_O + bh * 1096;
    const u16* kb = smem + K_O + bh * 1088;
    const int swr = (rowc & 7) << 3;
    f32x16 acc = {};
#pragma unroll
    for (int ks = 0; ks < 4; ++ks) {
      int off = (ks * 16 + lh * 8) ^ swr;
      short8 afr = *(const short8*)(qb + rowc * 64 + off);
      short8 bfr = *(const short8*)(kb + rowc * 64 + off);
      acc = __builtin_amdgcn_mfma_f32_32x32x16_bf16(afr, bfr, acc, 0, 0, 0);
    }
    if (l31 < 17) {
      float* Sb = Sf + bh * 289 + l31;
#pragma unroll
      for (int g = 0; g < 16; ++g) {
        int I = (g & 3) + 8 * (g >> 2) + 4 * lh;
        if (I < 17) Sb[I * 17] = acc[g];
      }
    }
  }
  for (int I = wv; I < 17; I += 4) {
    int bhA = l31 < 3 ? l31 : 2;
    const u16* qb = smem + Q_O + bhA * 1096 + I * 64;
    const int swz = (I & 7) << 3;
    float mpav = (l31 < 17) ? mpa[I * 17 + l31] : 0.f;
    f32x16 acc = {};
#pragma unroll
    for (int ks = 0; ks < 4; ++ks) {
      short8 afr = *(const short8*)(qb + ((ks * 16 + lh * 8) ^ swz));
      short8 bfr = *(const short8*)(krelf + ((size_t)(I * 4 + ks) * 64 + lane) * 8);
      acc = __builtin_amdgcn_mfma_f32_32x32x16_bf16(afr, bfr, acc, 0, 0, 0);
    }
    if (l31 < 17) {
#pragma unroll
      for (int g = 0; g < 16; ++g) {
        int bh = (g & 3) + 8 * (g >> 2) + 4 * lh;
        if (bh < 3) Sf2[bh * 289 + I * 17 + l31] = acc[g] + mpav;
      }
    }
  }
  if (tid < 51) dropl[tid] = drv;
  bar_lgkm();   // S complete; k dead -> wbf may overlay

  // ---- softmax + dropout renorm -> wbf; 4 threads/row (204 threads),
  //      cols J = sub + 4i; row value = Sf(QK) + Sf2(rel+mpa) + gmr5(gm) ----
  if (tid < 204) {
    int r = tid >> 2, sub = tid & 3;
    int bh = r / 17, I = r - bh * 17;
    const float* Srow  = Sf  + bh * 289 + I * 17;
    const float* S2row = Sf2 + bh * 289 + I * 17;
    float lv[5];
    float mx = -3.4e38f;
#pragma unroll
    for (int i = 0; i < 5; ++i) {
      int J = sub + 4 * i;
      float v = -3.4e38f;
      if (J < 17) v = Srow[J] + S2row[J] + gmr5[i];
      lv[i] = v;
      mx = fmaxf(mx, v);
    }
    mx = fmaxf(mx, __shfl_xor(mx, 1, 4));
    mx = fmaxf(mx, __shfl_xor(mx, 2, 4));
    float s1 = 0.f;
#pragma unroll
    for (int i = 0; i < 5; ++i) {
      int J = sub + 4 * i;
      float e = 0.f;
      if (J < 17) e = __expf(lv[i] - mx);
      lv[i] = e; s1 += e;
    }
    s1 += __shfl_xor(s1, 1, 4);
    s1 += __shfl_xor(s1, 2, 4);
    float inv1 = 1.0f / s1, s2 = 0.f;
#pragma unroll
    for (int i = 0; i < 5; ++i) {
      int J = sub + 4 * i;
      float w2 = 0.f;
      if (J < 17) w2 = lv[i] * inv1 * dropl[bh * 17 + J];
      lv[i] = w2; s2 += w2;
    }
    s2 += __shfl_xor(s2, 1, 4);
    s2 += __shfl_xor(s2, 2, 4);
    float inv2 = 1.0f / (s2 + 1e-8f);
    u16* wr = wbf + r * 32;
    int swz = (I & 3) << 3;   // u16-unit swizzle, matches PV read
#pragma unroll
    for (int i = 0; i < 8; ++i) {
      int J = sub + 4 * i;
      u16 val = 0;
      if (J < 17) val = f2b(lv[i] * inv2);
      wr[J ^ swz] = val;
    }
  }
  bar_lgkm();

  // ---- PV -> ao (overlays dead Sf/Sf2 at XS_O, [17][200]); nt-tiles serialized;
  //      v B-frags assembled via conflict-free ds_read_u16 from [17][64] slots ----
  if (wv < 3) {
    int bh = wv;
    const u16* wb = wbf + (bh * 17 + rowc) * 32;
    int sw = (rowc & 3) << 3;   // u16 units
    short8 wa0 = *(const short8*)(wb + ((lh * 8) ^ sw));
    short8 wa1 = *(const short8*)(wb + ((lh * 8 + 16) ^ sw));
    const u16* vb = smem + V_O + bh * 1088;
#pragma unroll
    for (int nt = 0; nt < 2; ++nt) {
      int d = nt * 32 + l31;
      short8 v0;
#pragma unroll
      for (int i = 0; i < 8; ++i) v0[i] = (short)vb[(lh * 8 + i) * 64 + d];
      f32x16 acc = {};
      acc = __builtin_amdgcn_mfma_f32_32x32x16_bf16(wa0, v0, acc, 0, 0, 0);
      short8 v1 = {};
      if (lh == 0) v1[0] = (short)vb[16 * 64 + d];
      acc = __builtin_amdgcn_mfma_f32_32x32x16_bf16(wa1, v1, acc, 0, 0, 0);
#pragma unroll
      for (int g = 0; g < 16; ++g) {
        int I = (g & 3) + 8 * (g >> 2) + 4 * lh;
        if (I < 17) smem[XS_O + I * 200 + bh * 64 + d] = f2b(acc[g]);
      }
    }
  }
  bar_lgkm();

  // ---- out-proj: 12 n-tiles across 4 waves; B-frags reg-resident over 2 M-tiles.
  //      A = ao at XS_O; rows >=17 read in-bounds garbage -> discarded ----
  float* outb = out + (size_t)blk * 17 * 192;
  for (int n = wv; n < 12; n += 4) {
    const int nc = n * 16 + lrow;
    short8 bfr[6];
#pragma unroll
    for (int kk = 0; kk < 6; ++kk)
      bfr[kk] = *(const short8*)(wcN + (size_t)nc * 192 + kk * 32 + kgrp);
    const float bias = bc[nc];
#pragma unroll
    for (int m = 0; m < 2; ++m) {
      f32x4 acc = {};
#pragma unroll
      for (int kk = 0; kk < 6; ++kk) {
        short8 a = *(const short8*)(smem + XS_O + (m * 16 + lrow) * 200 + kk * 32 + kgrp);
        acc = __builtin_amdgcn_mfma_f32_16x16x32_bf16(a, bfr[kk], acc, 0, 0, 0);
      }
#pragma unroll
      for (int j = 0; j < 4; ++j) {
        int r = m * 16 + lg * 4 + j;
        if (r < 17) outb[(size_t)r * 192 + nc] = acc[j] + bias;
      }
    }
  }
}

extern "C" void kernel_launch(void* const* d_in, const int* in_sizes, int n_in,
                              void* d_out, int out_size, void* d_ws, size_t ws_size,
                              hipStream_t stream) {
  const float* x    = (const float*)d_in[0];
  const float* mask = (const float*)d_in[1];
  const float* gm   = (const float*)d_in[2];
  const float* drop = (const float*)d_in[3];
  const float* qkvw = (const float*)d_in[4];
  const float* qkvb = (const float*)d_in[5];
  const float* attw = (const float*)d_in[6];
  const float* attb = (const float*)d_in[7];
  const float* krel = (const float*)d_in[8];
  const float* krd  = (const float*)d_in[9];
  const float* PA   = (const float*)d_in[10];
  const float* nn1w = (const float*)d_in[11];
  const float* nn1b = (const float*)d_in[12];
  char* ws = (char*)d_ws;
  float* out = (float*)d_out;

  prep_kernel<<<600, 256, 0, stream>>>(qkvw, attw, attb, nn1w, nn1b, krel, krd, mask, PA, ws);

  const u16* wN    = (const u16*)(ws + WN_OFF);
  const u16* wcN   = (const u16*)(ws + WCN_OFF);
  const float* bc  = (const float*)(ws + BC_OFF);
  const u16* krelf = (const u16*)(ws + KRELF_OFF);
  const float* mpa = (const float*)(ws + MPA_OFF);

  fused_kernel<<<NB_TOT, 256, 0, stream>>>(x, gm, drop, qkvb, wN, wcN, bc, krelf, mpa, out);
}

// Round 8
// 192.164 us; speedup vs baseline: 1.5779x; 1.5779x over previous
//
#include <hip/hip_runtime.h>

typedef __attribute__((ext_vector_type(8))) short short8;
typedef __attribute__((ext_vector_type(4))) float f32x4;
typedef __attribute__((ext_vector_type(16))) float f32x16;
typedef unsigned short u16;
typedef unsigned int u32;

#define NB_TOT 8192
#define DIM 192

// ws byte offsets (prep outputs only)
#define WN_OFF    0          // [576][192] bf16 qkv_w (n-major)
#define WCN_OFF   221184     // [192][192] bf16 nn1_w@attn_w (n-major)
#define BC_OFF    294912     // [192] f32
#define KRELF_OFF 295680     // [17][4][64][8] bf16 rel B-frags
#define MPA_OFF   365312     // [289] f32 mask*PA

// fused LDS (u16 units), block = 2 batches (34 rows, 6 bh), 512 threads (8 waves)
// 53,152 B -> alloc 53,248 (v5-proven); layout:
//   XSF @ 0     : x[34][200] bf16 (GEMM A-rows >=34 read in-bounds garbage, discarded)
//                 overlay1: Sf f32[1734] @0 + Sf2 f32[1734] @ u16 3468
//                 overlay2: ao [34][200] (born at PV, read by out-proj)
//   K   @ 6944  : k slots [bh][17][64], swz(I)=((I&7)<<3)^((I&8)<<1), stride 1088
//                 overlay: wbf u16[102*40] + dropl f32[102] (k dead after merged phase)
//   V   @ 13472 : v slots [bh][64][17] D-MAJOR (conflict-free stores+gathers), stride 1088
//   Q   @ 20000 : q slots [bh][17][64], swz as K, stride 1096 (8-u16 inter-slot pad)
#define XS_O  0
#define SF2_U16 3468
#define K_O   6944
#define V_O   13472
#define Q_O   20000
#define SMEM_U16 26576

__device__ __forceinline__ u16 f2b(float f) {
  u32 u = __float_as_uint(f);
  u32 r = u + 0x7FFFu + ((u >> 16) & 1u);  // RNE
  return (u16)(r >> 16);
}

__device__ __forceinline__ int swzqk(int I) {          // row-dependent d-xor, bits 3-5
  return ((I & 7) << 3) ^ ((I & 8) << 1);
}

// LDS-only barrier (global ops have register data-deps; final stores need no drain)
__device__ __forceinline__ void bar_lgkm() {
  asm volatile("s_waitcnt lgkmcnt(0)" ::: "memory");
  __builtin_amdgcn_s_barrier();
  asm volatile("" ::: "memory");
}

__global__ void prep_kernel(const float* __restrict__ qkv_w,
                            const float* __restrict__ attn_w,
                            const float* __restrict__ attn_b,
                            const float* __restrict__ nn1_w,
                            const float* __restrict__ nn1_b,
                            const float* __restrict__ key_rel,
                            const float* __restrict__ krd,
                            const float* __restrict__ mask,
                            const float* __restrict__ PA,
                            char* __restrict__ ws) {
  u16* wN    = (u16*)(ws + WN_OFF);
  u16* wcN   = (u16*)(ws + WCN_OFF);
  float* bc  = (float*)(ws + BC_OFF);
  u16* krelf = (u16*)(ws + KRELF_OFF);
  float* mpa = (float*)(ws + MPA_OFF);
  for (int idx = blockIdx.x * 256 + threadIdx.x; idx < 152289; idx += gridDim.x * 256) {
    if (idx < 110592) {
      wN[idx] = f2b(qkv_w[idx]);
    } else if (idx < 147456) {
      int t2 = idx - 110592; int n = t2 / 192, k = t2 - n * 192;
      float a = 0.f;
      for (int t = 0; t < 192; ++t) a = fmaf(nn1_w[n * 192 + t], attn_w[t * 192 + k], a);
      wcN[n * 192 + k] = f2b(a);
    } else if (idx < 147648) {
      int n = idx - 147456; float a = nn1_b[n];
      for (int t = 0; t < 192; ++t) a = fmaf(nn1_w[n * 192 + t], attn_b[t], a);
      bc[n] = a;
    } else if (idx < 152000) {
      int t = idx - 147648;              // ((I*4+ks)*64 + lane)
      int lane = t & 63, ks = (t >> 6) & 3, I = t >> 8;
      int J = lane & 31;
      int d0 = ks * 16 + (lane >> 5) * 8;
      u16 vals[8];
#pragma unroll
      for (int i = 0; i < 8; ++i) {
        float v = 0.f;
        if (J <= 16) {
          if (J == I) v = krd[d0 + i];
          else { int tt = 17 * I + J; int p = tt - tt / 18 - 1; v = key_rel[p * 64 + d0 + i]; }
        }
        vals[i] = f2b(v);
      }
      u32 w0 = vals[0] | ((u32)vals[1] << 16), w1 = vals[2] | ((u32)vals[3] << 16);
      u32 w2 = vals[4] | ((u32)vals[5] << 16), w3 = vals[6] | ((u32)vals[7] << 16);
      uint4 pk; pk.x = w0; pk.y = w1; pk.z = w2; pk.w = w3;
      *(uint4*)(krelf + (size_t)t * 8) = pk;
    } else {
      int i = idx - 152000; mpa[i] = mask[i] * PA[i];
    }
  }
}

// ---------------- fused v10: v7 shell + per-wave LDS efficiency ----------------
__global__ __launch_bounds__(512, 4)
void fused_kernel(const float* __restrict__ x, const float* __restrict__ gm,
                  const float* __restrict__ drop, const float* __restrict__ qkv_b,
                  const u16* __restrict__ wN, const u16* __restrict__ wcN,
                  const float* __restrict__ bc, const u16* __restrict__ krelf,
                  const float* __restrict__ mpa, float* __restrict__ out) {
  __shared__ u16 smem[SMEM_U16];
  float* const Sf    = (float*)(smem + XS_O);        // 1734 f32 overlay (after GEMM)
  float* const Sf2   = (float*)(smem + SF2_U16);     // 1734 f32 (rel + mpa)
  u16*   const wbf   = smem + K_O;                   // 102*40 u16 overlay (after merged)
  float* const dropl = (float*)(smem + K_O + 4080);  // 102 f32, after wbf in dead-K

  const int tid = threadIdx.x;
  const int blk = blockIdx.x;
  const int lane = tid & 63;
  const int l31 = lane & 31;
  const int lh = lane >> 5;
  const int wv = tid >> 6;

  // ---- prefetch: drop (1 reg) + gm softmax-slice (5 regs/thread) ----
  float drv = 0.f;
  if (tid < 102) drv = drop[(size_t)blk * 102 + tid];
  float gmr5[5] = {0.f, 0.f, 0.f, 0.f, 0.f};
  if (tid < 408) {
    int r = tid >> 2, sub = tid & 3;
    int bh = r / 17, I = r - bh * 17;
    const float* gmrow = gm + (size_t)blk * 1734 + bh * 289 + I * 17;
#pragma unroll
    for (int i = 0; i < 5; ++i) {
      int J = sub + 4 * i;
      if (J < 17) gmr5[i] = gmrow[J];
    }
  }

  // ---- stage x -> LDS bf16 [34][200] ----
  const float* xb = x + (size_t)blk * 34 * 192;
  for (int idx = tid; idx < 1632; idx += 512) {
    int row = idx / 48, k4 = (idx - row * 48) * 4;
    float4 v = *(const float4*)(xb + row * 192 + k4);
    u16 p[4] = {f2b(v.x), f2b(v.y), f2b(v.z), f2b(v.w)};
    *(uint2*)(smem + XS_O + row * 200 + k4) = *(uint2*)p;
  }
  bar_lgkm();

  const int lrow = tid & 15, lg = (tid >> 4) & 3, kgrp = lg * 8;

  // ---- qkv GEMM: 18 N-PAIRS (2 tiles share A-frag reads) across 8 waves.
  //      A-reads 81->45 per wave; 2 indep MFMA chains. Pairs never straddle
  //      q/k/v boundaries (12, 24 are even). Rows >=34 garbage -> discarded ----
  for (int Np = wv; Np < 18; Np += 8) {
    const int t0 = Np * 2;
    const int c0 = t0 * 16;
    const int which = c0 / 192;
    const int hd0 = c0 - which * 192;
    const int h0 = hd0 >> 6,          h1 = (hd0 + 16) >> 6;
    const int d0 = (hd0 & 63) + lrow, d1 = ((hd0 + 16) & 63) + lrow;
    const u16* wB0 = wN + (size_t)(c0 + lrow) * 192;
    const u16* wB1 = wB0 + 16 * 192;
    short8 bfr0[6], bfr1[6];
#pragma unroll
    for (int kk = 0; kk < 6; ++kk) {
      bfr0[kk] = *(const short8*)(wB0 + kk * 32 + kgrp);
      bfr1[kk] = *(const short8*)(wB1 + kk * 32 + kgrp);
    }
    const float bias0 = qkv_b[c0 + lrow], bias1 = qkv_b[c0 + 16 + lrow];
    const float scale = which ? 1.0f : 0.125f;
#pragma unroll
    for (int m = 0; m < 3; ++m) {
      f32x4 acc0 = {}, acc1 = {};
#pragma unroll
      for (int kk = 0; kk < 6; ++kk) {
        short8 a = *(const short8*)(smem + XS_O + (m * 16 + lrow) * 200 + kk * 32 + kgrp);
        acc0 = __builtin_amdgcn_mfma_f32_16x16x32_bf16(a, bfr0[kk], acc0, 0, 0, 0);
        acc1 = __builtin_amdgcn_mfma_f32_16x16x32_bf16(a, bfr1[kk], acc1, 0, 0, 0);
      }
#pragma unroll
      for (int j = 0; j < 4; ++j) {
        int r = m * 16 + lg * 4 + j;
        if (r < 34) {
          int bi = r >= 17 ? 1 : 0, I = r - bi * 17;
          int slot = bi * 3 + h0, slot1 = bi * 3 + h1;
          u16 v0 = f2b((acc0[j] + bias0) * scale);
          u16 v1 = f2b((acc1[j] + bias1) * scale);
          if (which == 0) {
            smem[Q_O + slot  * 1096 + I * 64 + (d0 ^ swzqk(I))] = v0;
            smem[Q_O + slot1 * 1096 + I * 64 + (d1 ^ swzqk(I))] = v1;
          } else if (which == 1) {
            smem[K_O + slot  * 1088 + I * 64 + (d0 ^ swzqk(I))] = v0;
            smem[K_O + slot1 * 1088 + I * 64 + (d1 ^ swzqk(I))] = v1;
          } else {           // V: d-major [64][17] -> conflict-free stores
            smem[V_O + slot  * 1088 + d0 * 17 + I] = v0;
            smem[V_O + slot1 * 1088 + d1 * 17 + I] = v1;
          }
        }
      }
    }
  }
  bar_lgkm();   // q/k/v complete; x dead -> Sf/Sf2 may overlay

  const int rowc = l31 < 16 ? l31 : 16;

  // ==== MERGED phase: QK^T (waves 0-5, -> Sf, C-init 0) || rel+mpa (all waves,
  //      -> Sf2) || dropl park. Disjoint output buffers -> no ordering needed. ====
  if (wv < 6) {
    int bh = wv;
    const u16* qb = smem + Q_O + bh * 1096;
    const u16* kb = smem + K_O + bh * 1088;
    const int swr = swzqk(rowc);
    f32x16 acc = {};
#pragma unroll
    for (int ks = 0; ks < 4; ++ks) {
      int off = (ks * 16 + lh * 8) ^ swr;
      short8 afr = *(const short8*)(qb + rowc * 64 + off);
      short8 bfr = *(const short8*)(kb + rowc * 64 + off);
      acc = __builtin_amdgcn_mfma_f32_32x32x16_bf16(afr, bfr, acc, 0, 0, 0);
    }
    if (l31 < 17) {
      float* Sb = Sf + bh * 289 + l31;
#pragma unroll
      for (int g = 0; g < 16; ++g) {
        int I = (g & 3) + 8 * (g >> 2) + 4 * lh;
        if (I < 17) Sb[I * 17] = acc[g];
      }
    }
  }
  for (int I = wv; I < 17; I += 8) {
    int bhA = l31 < 6 ? l31 : 5;
    const u16* qb = smem + Q_O + bhA * 1096 + I * 64;
    const int swz = swzqk(I);
    float mpav = (l31 < 17) ? mpa[I * 17 + l31] : 0.f;
    f32x16 acc = {};
#pragma unroll
    for (int ks = 0; ks < 4; ++ks) {
      short8 afr = *(const short8*)(qb + ((ks * 16 + lh * 8) ^ swz));
      short8 bfr = *(const short8*)(krelf + ((size_t)(I * 4 + ks) * 64 + lane) * 8);
      acc = __builtin_amdgcn_mfma_f32_32x32x16_bf16(afr, bfr, acc, 0, 0, 0);
    }
    if (l31 < 17) {
#pragma unroll
      for (int g = 0; g < 16; ++g) {
        int bh = (g & 3) + 8 * (g >> 2) + 4 * lh;
        if (bh < 6) Sf2[bh * 289 + I * 17 + l31] = acc[g] + mpav;
      }
    }
  }
  if (tid < 102) dropl[tid] = drv;
  bar_lgkm();   // S complete; k dead -> wbf may overlay

  // ---- softmax + dropout renorm -> wbf (stride 40); 4 threads/row (408 thr),
  //      cols J = sub + 4i; row value = Sf(QK) + Sf2(rel+mpa) + gmr5(gm) ----
  if (tid < 408) {
    int r = tid >> 2, sub = tid & 3;
    int bh = r / 17, I = r - bh * 17;
    const float* Srow  = Sf  + bh * 289 + I * 17;
    const float* S2row = Sf2 + bh * 289 + I * 17;
    float lv[5];
    float mx = -3.4e38f;
#pragma unroll
    for (int i = 0; i < 5; ++i) {
      int J = sub + 4 * i;
      float v = -3.4e38f;
      if (J < 17) v = Srow[J] + S2row[J] + gmr5[i];
      lv[i] = v;
      mx = fmaxf(mx, v);
    }
    mx = fmaxf(mx, __shfl_xor(mx, 1, 4));
    mx = fmaxf(mx, __shfl_xor(mx, 2, 4));
    float s1 = 0.f;
#pragma unroll
    for (int i = 0; i < 5; ++i) {
      int J = sub + 4 * i;
      float e = 0.f;
      if (J < 17) e = __expf(lv[i] - mx);
      lv[i] = e; s1 += e;
    }
    s1 += __shfl_xor(s1, 1, 4);
    s1 += __shfl_xor(s1, 2, 4);
    float inv1 = 1.0f / s1, s2 = 0.f;
#pragma unroll
    for (int i = 0; i < 5; ++i) {
      int J = sub + 4 * i;
      float w2 = 0.f;
      if (J < 17) w2 = lv[i] * inv1 * dropl[bh * 17 + J];
      lv[i] = w2; s2 += w2;
    }
    s2 += __shfl_xor(s2, 1, 4);
    s2 += __shfl_xor(s2, 2, 4);
    float inv2 = 1.0f / (s2 + 1e-8f);
    u16* wr = wbf + r * 40;
    int swz = (I & 3) << 3;   // u16-unit swizzle, matches PV read
#pragma unroll
    for (int i = 0; i < 8; ++i) {
      int J = sub + 4 * i;
      u16 val = 0;
      if (J < 17) val = f2b(lv[i] * inv2);
      wr[J ^ swz] = val;
    }
  }
  bar_lgkm();

  // ---- PV -> ao (overlays dead Sf/Sf2 at XS_O, [34][200]); V gathers are
  //      k-contig d-major (bank-spread, ~conflict-free) ----
  if (wv < 6) {
    int bh = wv;
    const u16* wb = wbf + (bh * 17 + rowc) * 40;
    int sw = (rowc & 3) << 3;   // u16 units
    short8 wa0 = *(const short8*)(wb + ((lh * 8) ^ sw));
    short8 wa1 = *(const short8*)(wb + ((lh * 8 + 16) ^ sw));
    int bi = bh >= 3 ? 1 : 0, h = bh - bi * 3;
    const u16* vb = smem + V_O + bh * 1088;
#pragma unroll
    for (int nt = 0; nt < 2; ++nt) {
      int d = nt * 32 + l31;
      short8 v0;
#pragma unroll
      for (int i = 0; i < 8; ++i) v0[i] = (short)vb[d * 17 + lh * 8 + i];
      f32x16 acc = {};
      acc = __builtin_amdgcn_mfma_f32_32x32x16_bf16(wa0, v0, acc, 0, 0, 0);
      short8 v1 = {};
      if (lh == 0) v1[0] = (short)vb[d * 17 + 16];
      acc = __builtin_amdgcn_mfma_f32_32x32x16_bf16(wa1, v1, acc, 0, 0, 0);
#pragma unroll
      for (int g = 0; g < 16; ++g) {
        int I = (g & 3) + 8 * (g >> 2) + 4 * lh;
        if (I < 17) smem[XS_O + (bi * 17 + I) * 200 + h * 64 + d] = f2b(acc[g]);
      }
    }
  }
  bar_lgkm();

  // ---- out-proj: 6 N-PAIRS across waves 0-5 (A-frag reads shared);
  //      A = ao at XS_O; rows >=34 read in-bounds garbage -> discarded ----
  float* outb = out + (size_t)blk * 34 * 192;
  if (wv < 6) {
    const int n0 = wv * 2;
    const int nc0 = n0 * 16 + lrow, nc1 = nc0 + 16;
    short8 bfr0[6], bfr1[6];
#pragma unroll
    for (int kk = 0; kk < 6; ++kk) {
      bfr0[kk] = *(const short8*)(wcN + (size_t)nc0 * 192 + kk * 32 + kgrp);
      bfr1[kk] = *(const short8*)(wcN + (size_t)nc1 * 192 + kk * 32 + kgrp);
    }
    const float bias0 = bc[nc0], bias1 = bc[nc1];
#pragma unroll
    for (int m = 0; m < 3; ++m) {
      f32x4 acc0 = {}, acc1 = {};
#pragma unroll
      for (int kk = 0; kk < 6; ++kk) {
        short8 a = *(const short8*)(smem + XS_O + (m * 16 + lrow) * 200 + kk * 32 + kgrp);
        acc0 = __builtin_amdgcn_mfma_f32_16x16x32_bf16(a, bfr0[kk], acc0, 0, 0, 0);
        acc1 = __builtin_amdgcn_mfma_f32_16x16x32_bf16(a, bfr1[kk], acc1, 0, 0, 0);
      }
#pragma unroll
      for (int j = 0; j < 4; ++j) {
        int r = m * 16 + lg * 4 + j;
        if (r < 34) {
          outb[(size_t)r * 192 + nc0] = acc0[j] + bias0;
          outb[(size_t)r * 192 + nc1] = acc1[j] + bias1;
        }
      }
    }
  }
}

extern "C" void kernel_launch(void* const* d_in, const int* in_sizes, int n_in,
                              void* d_out, int out_size, void* d_ws, size_t ws_size,
                              hipStream_t stream) {
  const float* x    = (const float*)d_in[0];
  const float* mask = (const float*)d_in[1];
  const float* gm   = (const float*)d_in[2];
  const float* drop = (const float*)d_in[3];
  const float* qkvw = (const float*)d_in[4];
  const float* qkvb = (const float*)d_in[5];
  const float* attw = (const float*)d_in[6];
  const float* attb = (const float*)d_in[7];
  const float* krel = (const float*)d_in[8];
  const float* krd  = (const float*)d_in[9];
  const float* PA   = (const float*)d_in[10];
  const float* nn1w = (const float*)d_in[11];
  const float* nn1b = (const float*)d_in[12];
  char* ws = (char*)d_ws;
  float* out = (float*)d_out;

  prep_kernel<<<600, 256, 0, stream>>>(qkvw, attw, attb, nn1w, nn1b, krel, krd, mask, PA, ws);

  const u16* wN    = (const u16*)(ws + WN_OFF);
  const u16* wcN   = (const u16*)(ws + WCN_OFF);
  const float* bc  = (const float*)(ws + BC_OFF);
  const u16* krelf = (const u16*)(ws + KRELF_OFF);
  const float* mpa = (const float*)(ws + MPA_OFF);

  fused_kernel<<<NB_TOT / 2, 512, 0, stream>>>(x, gm, drop, qkvb, wN, wcN, bc, krelf, mpa, out);
}

// Round 11
// 191.138 us; speedup vs baseline: 1.5864x; 1.0054x over previous
//
#include <hip/hip_runtime.h>

typedef __attribute__((ext_vector_type(8))) short short8;
typedef __attribute__((ext_vector_type(4))) float f32x4;
typedef __attribute__((ext_vector_type(16))) float f32x16;
typedef unsigned short u16;
typedef unsigned int u32;

#define NB_TOT 8192
#define DIM 192

// ws byte offsets (prep outputs only)
#define WN_OFF    0          // [576][192] bf16 qkv_w (n-major)
#define WCN_OFF   221184     // [192][192] bf16 nn1_w@attn_w (n-major)
#define BC_OFF    294912     // [192] f32
#define KRELF_OFF 295680     // [17][4][64][8] bf16 rel B-frags
#define MPA_OFF   365312     // [289] f32 mask*PA

// fused LDS (u16 units), block = 2 batches (34 rows, 6 bh), 512 threads (8 waves)
// 58,528 B -> alloc 58,624; x2 fits 160 KiB => 2 blocks/CU:
//   XSF @ 0     : x[34][200] bf16 (GEMM A-rows >=34 read in-bounds garbage, discarded)
//                 overlay1: Sf f32[1734] @0 + Sf2 f32[1734] @ u16 3468
//                 overlay2: ao [34][200] (born at PV, read by out-proj)
//   K   @ 6944  : k slots [bh][17][64], swz(I)=((I&7)<<3)^((I&8)<<1), stride 1088
//                 overlay: wbf u16[102*40] + dropl f32[102] (k dead after merged phase)
//   V   @ 13472 : v slots [bh][64][24] d-major (b128 PV gathers; J=17..23 garbage,
//                 never read), stride 1536
//   Q   @ 22688 : q slots [bh][17][64], swz as K, stride 1096 (8-u16 inter-slot pad)
#define XS_O  0
#define SF2_U16 3468
#define K_O   6944
#define V_O   13472
#define Q_O   22688
#define SMEM_U16 29264

__device__ __forceinline__ u16 f2b(float f) {
  u32 u = __float_as_uint(f);
  u32 r = u + 0x7FFFu + ((u >> 16) & 1u);  // RNE
  return (u16)(r >> 16);
}

__device__ __forceinline__ int swzqk(int I) {          // row-dependent d-xor, bits 3-5
  return ((I & 7) << 3) ^ ((I & 8) << 1);
}

// LDS-only barrier (global ops have register data-deps; final stores need no drain)
__device__ __forceinline__ void bar_lgkm() {
  asm volatile("s_waitcnt lgkmcnt(0)" ::: "memory");
  __builtin_amdgcn_s_barrier();
  asm volatile("" ::: "memory");
}

__global__ void prep_kernel(const float* __restrict__ qkv_w,
                            const float* __restrict__ attn_w,
                            const float* __restrict__ attn_b,
                            const float* __restrict__ nn1_w,
                            const float* __restrict__ nn1_b,
                            const float* __restrict__ key_rel,
                            const float* __restrict__ krd,
                            const float* __restrict__ mask,
                            const float* __restrict__ PA,
                            char* __restrict__ ws) {
  u16* wN    = (u16*)(ws + WN_OFF);
  u16* wcN   = (u16*)(ws + WCN_OFF);
  float* bc  = (float*)(ws + BC_OFF);
  u16* krelf = (u16*)(ws + KRELF_OFF);
  float* mpa = (float*)(ws + MPA_OFF);
  for (int idx = blockIdx.x * 256 + threadIdx.x; idx < 152289; idx += gridDim.x * 256) {
    if (idx < 110592) {
      wN[idx] = f2b(qkv_w[idx]);
    } else if (idx < 147456) {
      int t2 = idx - 110592; int n = t2 / 192, k = t2 - n * 192;
      float a = 0.f;
      for (int t = 0; t < 192; ++t) a = fmaf(nn1_w[n * 192 + t], attn_w[t * 192 + k], a);
      wcN[n * 192 + k] = f2b(a);
    } else if (idx < 147648) {
      int n = idx - 147456; float a = nn1_b[n];
      for (int t = 0; t < 192; ++t) a = fmaf(nn1_w[n * 192 + t], attn_b[t], a);
      bc[n] = a;
    } else if (idx < 152000) {
      int t = idx - 147648;              // ((I*4+ks)*64 + lane)
      int lane = t & 63, ks = (t >> 6) & 3, I = t >> 8;
      int J = lane & 31;
      int d0 = ks * 16 + (lane >> 5) * 8;
      u16 vals[8];
#pragma unroll
      for (int i = 0; i < 8; ++i) {
        float v = 0.f;
        if (J <= 16) {
          if (J == I) v = krd[d0 + i];
          else { int tt = 17 * I + J; int p = tt - tt / 18 - 1; v = key_rel[p * 64 + d0 + i]; }
        }
        vals[i] = f2b(v);
      }
      u32 w0 = vals[0] | ((u32)vals[1] << 16), w1 = vals[2] | ((u32)vals[3] << 16);
      u32 w2 = vals[4] | ((u32)vals[5] << 16), w3 = vals[6] | ((u32)vals[7] << 16);
      uint4 pk; pk.x = w0; pk.y = w1; pk.z = w2; pk.w = w3;
      *(uint4*)(krelf + (size_t)t * 8) = pk;
    } else {
      int i = idx - 152000; mpa[i] = mask[i] * PA[i];
    }
  }
}

// ---- fused v13: exact v10 + V[64][24] b128 PV gathers (NO cvtpk anywhere) ----
__global__ __launch_bounds__(512, 4)
void fused_kernel(const float* __restrict__ x, const float* __restrict__ gm,
                  const float* __restrict__ drop, const float* __restrict__ qkv_b,
                  const u16* __restrict__ wN, const u16* __restrict__ wcN,
                  const float* __restrict__ bc, const u16* __restrict__ krelf,
                  const float* __restrict__ mpa, float* __restrict__ out) {
  __shared__ u16 smem[SMEM_U16];
  float* const Sf    = (float*)(smem + XS_O);        // 1734 f32 overlay (after GEMM)
  float* const Sf2   = (float*)(smem + SF2_U16);     // 1734 f32 (rel + mpa)
  u16*   const wbf   = smem + K_O;                   // 102*40 u16 overlay (after merged)
  float* const dropl = (float*)(smem + K_O + 4080);  // 102 f32, after wbf in dead-K

  const int tid = threadIdx.x;
  const int blk = blockIdx.x;
  const int lane = tid & 63;
  const int l31 = lane & 31;
  const int lh = lane >> 5;
  const int wv = tid >> 6;

  // ---- prefetch: drop (1 reg) + gm softmax-slice (5 regs/thread) ----
  float drv = 0.f;
  if (tid < 102) drv = drop[(size_t)blk * 102 + tid];
  float gmr5[5] = {0.f, 0.f, 0.f, 0.f, 0.f};
  if (tid < 408) {
    int r = tid >> 2, sub = tid & 3;
    int bh = r / 17, I = r - bh * 17;
    const float* gmrow = gm + (size_t)blk * 1734 + bh * 289 + I * 17;
#pragma unroll
    for (int i = 0; i < 5; ++i) {
      int J = sub + 4 * i;
      if (J < 17) gmr5[i] = gmrow[J];
    }
  }

  // ---- stage x -> LDS bf16 [34][200] ----
  const float* xb = x + (size_t)blk * 34 * 192;
  for (int idx = tid; idx < 1632; idx += 512) {
    int row = idx / 48, k4 = (idx - row * 48) * 4;
    float4 v = *(const float4*)(xb + row * 192 + k4);
    u16 p[4] = {f2b(v.x), f2b(v.y), f2b(v.z), f2b(v.w)};
    *(uint2*)(smem + XS_O + row * 200 + k4) = *(uint2*)p;
  }
  bar_lgkm();

  const int lrow = tid & 15, lg = (tid >> 4) & 3, kgrp = lg * 8;

  // ---- qkv GEMM: 18 N-PAIRS (2 tiles share A-frag reads) across 8 waves.
  //      Pairs never straddle q/k/v boundaries. Rows >=34 garbage -> discarded ----
  for (int Np = wv; Np < 18; Np += 8) {
    const int c0 = Np * 32;
    const int which = c0 / 192;
    const int hd0 = c0 - which * 192;
    const int h0 = hd0 >> 6,          h1 = (hd0 + 16) >> 6;
    const int d0 = (hd0 & 63) + lrow, d1 = ((hd0 + 16) & 63) + lrow;
    const u16* wB0 = wN + (size_t)(c0 + lrow) * 192;
    const u16* wB1 = wB0 + 16 * 192;
    short8 bfr0[6], bfr1[6];
#pragma unroll
    for (int kk = 0; kk < 6; ++kk) {
      bfr0[kk] = *(const short8*)(wB0 + kk * 32 + kgrp);
      bfr1[kk] = *(const short8*)(wB1 + kk * 32 + kgrp);
    }
    const float bias0 = qkv_b[c0 + lrow], bias1 = qkv_b[c0 + 16 + lrow];
    const float scale = which ? 1.0f : 0.125f;
#pragma unroll
    for (int m = 0; m < 3; ++m) {
      f32x4 acc0 = {}, acc1 = {};
#pragma unroll
      for (int kk = 0; kk < 6; ++kk) {
        short8 a = *(const short8*)(smem + XS_O + (m * 16 + lrow) * 200 + kk * 32 + kgrp);
        acc0 = __builtin_amdgcn_mfma_f32_16x16x32_bf16(a, bfr0[kk], acc0, 0, 0, 0);
        acc1 = __builtin_amdgcn_mfma_f32_16x16x32_bf16(a, bfr1[kk], acc1, 0, 0, 0);
      }
#pragma unroll
      for (int j = 0; j < 4; ++j) {
        int r = m * 16 + lg * 4 + j;
        if (r < 34) {
          int bi = r >= 17 ? 1 : 0, I = r - bi * 17;
          int slot = bi * 3 + h0, slot1 = bi * 3 + h1;
          u16 v0 = f2b((acc0[j] + bias0) * scale);
          u16 v1 = f2b((acc1[j] + bias1) * scale);
          if (which == 0) {
            smem[Q_O + slot  * 1096 + I * 64 + (d0 ^ swzqk(I))] = v0;
            smem[Q_O + slot1 * 1096 + I * 64 + (d1 ^ swzqk(I))] = v1;
          } else if (which == 1) {
            smem[K_O + slot  * 1088 + I * 64 + (d0 ^ swzqk(I))] = v0;
            smem[K_O + slot1 * 1088 + I * 64 + (d1 ^ swzqk(I))] = v1;
          } else {           // V: d-major [64][24]
            smem[V_O + slot  * 1536 + d0 * 24 + I] = v0;
            smem[V_O + slot1 * 1536 + d1 * 24 + I] = v1;
          }
        }
      }
    }
  }
  bar_lgkm();   // q/k/v complete; x dead -> Sf/Sf2 may overlay

  const int rowc = l31 < 16 ? l31 : 16;

  // ==== MERGED phase: QK^T (waves 0-5, -> Sf, C-init 0) || rel+mpa (all waves,
  //      -> Sf2) || dropl park. Disjoint output buffers -> no ordering needed. ====
  if (wv < 6) {
    int bh = wv;
    const u16* qb = smem + Q_O + bh * 1096;
    const u16* kb = smem + K_O + bh * 1088;
    const int swr = swzqk(rowc);
    f32x16 acc = {};
#pragma unroll
    for (int ks = 0; ks < 4; ++ks) {
      int off = (ks * 16 + lh * 8) ^ swr;
      short8 afr = *(const short8*)(qb + rowc * 64 + off);
      short8 bfr = *(const short8*)(kb + rowc * 64 + off);
      acc = __builtin_amdgcn_mfma_f32_32x32x16_bf16(afr, bfr, acc, 0, 0, 0);
    }
    if (l31 < 17) {
      float* Sb = Sf + bh * 289 + l31;
#pragma unroll
      for (int g = 0; g < 16; ++g) {
        int I = (g & 3) + 8 * (g >> 2) + 4 * lh;
        if (I < 17) Sb[I * 17] = acc[g];
      }
    }
  }
  for (int I = wv; I < 17; I += 8) {
    int bhA = l31 < 6 ? l31 : 5;
    const u16* qb = smem + Q_O + bhA * 1096 + I * 64;
    const int swz = swzqk(I);
    float mpav = (l31 < 17) ? mpa[I * 17 + l31] : 0.f;
    f32x16 acc = {};
#pragma unroll
    for (int ks = 0; ks < 4; ++ks) {
      short8 afr = *(const short8*)(qb + ((ks * 16 + lh * 8) ^ swz));
      short8 bfr = *(const short8*)(krelf + ((size_t)(I * 4 + ks) * 64 + lane) * 8);
      acc = __builtin_amdgcn_mfma_f32_32x32x16_bf16(afr, bfr, acc, 0, 0, 0);
    }
    if (l31 < 17) {
#pragma unroll
      for (int g = 0; g < 16; ++g) {
        int bh = (g & 3) + 8 * (g >> 2) + 4 * lh;
        if (bh < 6) Sf2[bh * 289 + I * 17 + l31] = acc[g] + mpav;
      }
    }
  }
  if (tid < 102) dropl[tid] = drv;
  bar_lgkm();   // S complete; k dead -> wbf may overlay

  // ---- softmax + dropout renorm -> wbf (stride 40); 4 threads/row (408 thr),
  //      cols J = sub + 4i; row value = Sf(QK) + Sf2(rel+mpa) + gmr5(gm) ----
  if (tid < 408) {
    int r = tid >> 2, sub = tid & 3;
    int bh = r / 17, I = r - bh * 17;
    const float* Srow  = Sf  + bh * 289 + I * 17;
    const float* S2row = Sf2 + bh * 289 + I * 17;
    float lv[5];
    float mx = -3.4e38f;
#pragma unroll
    for (int i = 0; i < 5; ++i) {
      int J = sub + 4 * i;
      float v = -3.4e38f;
      if (J < 17) v = Srow[J] + S2row[J] + gmr5[i];
      lv[i] = v;
      mx = fmaxf(mx, v);
    }
    mx = fmaxf(mx, __shfl_xor(mx, 1, 4));
    mx = fmaxf(mx, __shfl_xor(mx, 2, 4));
    float s1 = 0.f;
#pragma unroll
    for (int i = 0; i < 5; ++i) {
      int J = sub + 4 * i;
      float e = 0.f;
      if (J < 17) e = __expf(lv[i] - mx);
      lv[i] = e; s1 += e;
    }
    s1 += __shfl_xor(s1, 1, 4);
    s1 += __shfl_xor(s1, 2, 4);
    float inv1 = 1.0f / s1, s2 = 0.f;
#pragma unroll
    for (int i = 0; i < 5; ++i) {
      int J = sub + 4 * i;
      float w2 = 0.f;
      if (J < 17) w2 = lv[i] * inv1 * dropl[bh * 17 + J];
      lv[i] = w2; s2 += w2;
    }
    s2 += __shfl_xor(s2, 1, 4);
    s2 += __shfl_xor(s2, 2, 4);
    float inv2 = 1.0f / (s2 + 1e-8f);
    u16* wr = wbf + r * 40;
    int swz = (I & 3) << 3;   // u16-unit swizzle, matches PV read
#pragma unroll
    for (int i = 0; i < 8; ++i) {
      int J = sub + 4 * i;
      u16 val = 0;
      if (J < 17) val = f2b(lv[i] * inv2);
      wr[J ^ swz] = val;
    }
  }
  bar_lgkm();

  // ---- PV -> ao (overlays dead Sf/Sf2 at XS_O, [34][200]); V gathers are
  //      b128 d-major reads (J<=15) + scalar J=16 tail; scalar f2b ao stores ----
  if (wv < 6) {
    int bh = wv;
    const u16* wb = wbf + (bh * 17 + rowc) * 40;
    int sw = (rowc & 3) << 3;   // u16 units
    short8 wa0 = *(const short8*)(wb + ((lh * 8) ^ sw));
    short8 wa1 = *(const short8*)(wb + ((lh * 8 + 16) ^ sw));
    int bi = bh >= 3 ? 1 : 0, h = bh - bi * 3;
    const u16* vb = smem + V_O + bh * 1536;
#pragma unroll
    for (int nt = 0; nt < 2; ++nt) {
      int d = nt * 32 + l31;
      short8 v0 = *(const short8*)(vb + d * 24 + lh * 8);   // J = lh*8..+7
      f32x16 acc = {};
      acc = __builtin_amdgcn_mfma_f32_32x32x16_bf16(wa0, v0, acc, 0, 0, 0);
      short8 v1 = {};
      if (lh == 0) v1[0] = (short)vb[d * 24 + 16];          // J = 16 tail
      acc = __builtin_amdgcn_mfma_f32_32x32x16_bf16(wa1, v1, acc, 0, 0, 0);
#pragma unroll
      for (int g = 0; g < 16; ++g) {
        int I = (g & 3) + 8 * (g >> 2) + 4 * lh;
        if (I < 17) smem[XS_O + (bi * 17 + I) * 200 + h * 64 + d] = f2b(acc[g]);
      }
    }
  }
  bar_lgkm();

  // ---- out-proj: 6 N-PAIRS across waves 0-5 (A-frag reads shared);
  //      A = ao at XS_O; rows >=34 read in-bounds garbage -> discarded ----
  float* outb = out + (size_t)blk * 34 * 192;
  if (wv < 6) {
    const int nc0 = wv * 32 + lrow, nc1 = nc0 + 16;
    short8 bfr0[6], bfr1[6];
#pragma unroll
    for (int kk = 0; kk < 6; ++kk) {
      bfr0[kk] = *(const short8*)(wcN + (size_t)nc0 * 192 + kk * 32 + kgrp);
      bfr1[kk] = *(const short8*)(wcN + (size_t)nc1 * 192 + kk * 32 + kgrp);
    }
    const float bias0 = bc[nc0], bias1 = bc[nc1];
#pragma unroll
    for (int m = 0; m < 3; ++m) {
      f32x4 acc0 = {}, acc1 = {};
#pragma unroll
      for (int kk = 0; kk < 6; ++kk) {
        short8 a = *(const short8*)(smem + XS_O + (m * 16 + lrow) * 200 + kk * 32 + kgrp);
        acc0 = __builtin_amdgcn_mfma_f32_16x16x32_bf16(a, bfr0[kk], acc0, 0, 0, 0);
        acc1 = __builtin_amdgcn_mfma_f32_16x16x32_bf16(a, bfr1[kk], acc1, 0, 0, 0);
      }
#pragma unroll
      for (int j = 0; j < 4; ++j) {
        int r = m * 16 + lg * 4 + j;
        if (r < 34) {
          outb[(size_t)r * 192 + nc0] = acc0[j] + bias0;
          outb[(size_t)r * 192 + nc1] = acc1[j] + bias1;
        }
      }
    }
  }
}

extern "C" void kernel_launch(void* const* d_in, const int* in_sizes, int n_in,
                              void* d_out, int out_size, void* d_ws, size_t ws_size,
                              hipStream_t stream) {
  const float* x    = (const float*)d_in[0];
  const float* mask = (const float*)d_in[1];
  const float* gm   = (const float*)d_in[2];
  const float* drop = (const float*)d_in[3];
  const float* qkvw = (const float*)d_in[4];
  const float* qkvb = (const float*)d_in[5];
  const float* attw = (const float*)d_in[6];
  const float* attb = (const float*)d_in[7];
  const float* krel = (const float*)d_in[8];
  const float* krd  = (const float*)d_in[9];
  const float* PA   = (const float*)d_in[10];
  const float* nn1w = (const float*)d_in[11];
  const float* nn1b = (const float*)d_in[12];
  char* ws = (char*)d_ws;
  float* out = (float*)d_out;

  prep_kernel<<<600, 256, 0, stream>>>(qkvw, attw, attb, nn1w, nn1b, krel, krd, mask, PA, ws);

  const u16* wN    = (const u16*)(ws + WN_OFF);
  const u16* wcN   = (const u16*)(ws + WCN_OFF);
  const float* bc  = (const float*)(ws + BC_OFF);
  const u16* krelf = (const u16*)(ws + KRELF_OFF);
  const float* mpa = (const float*)(ws + MPA_OFF);

  fused_kernel<<<NB_TOT / 2, 512, 0, stream>>>(x, gm, drop, qkvb, wN, wcN, bc, krelf, mpa, out);
}